// Round 1
// baseline (1157.801 us; speedup 1.0000x reference)
//
#include <hip/hip_runtime.h>
#include <hip/hip_bf16.h>
#include <stdint.h>

// Problem constants
#define T_SEQ 2048
#define DM    2048
#define NH    16
#define NKVH  4
#define HD    128
#define NBATCH 4
#define BT    (NBATCH * T_SEQ)   // 8192 rows of x
#define NQKV  3072               // 2048 (Q) + 512 (K) + 512 (V)
#define ATT_SCALE 0.08838834764831845f  // 1/sqrt(128)

typedef __attribute__((ext_vector_type(8))) short bf16x8;
typedef __attribute__((ext_vector_type(4))) float f32x4;
typedef __attribute__((ext_vector_type(8))) unsigned short ushort8;
typedef __attribute__((ext_vector_type(4))) unsigned short ushort4v;

static __device__ __forceinline__ unsigned short f2bf(float f) {
  __hip_bfloat16 h = __float2bfloat16(f);
  return __builtin_bit_cast(unsigned short, h);
}
static __device__ __forceinline__ float bf2f(unsigned short u) {
  unsigned int v = ((unsigned int)u) << 16;
  return __builtin_bit_cast(float, v);
}

#define GLDS16(g, l)                                                        \
  __builtin_amdgcn_global_load_lds(                                         \
      (const __attribute__((address_space(1))) void*)(g),                   \
      (__attribute__((address_space(3))) void*)(l), 16, 0, 0)

// ---------------------------------------------------------------- cast x
__global__ __launch_bounds__(256) void castx_k(const float* __restrict__ x,
                                               unsigned short* __restrict__ xb) {
  int i = (blockIdx.x * 256 + threadIdx.x) * 4;
  float4 v = *(const float4*)&x[i];
  ushort4v o;
  o[0] = f2bf(v.x); o[1] = f2bf(v.y); o[2] = f2bf(v.z); o[3] = f2bf(v.w);
  *(ushort4v*)&xb[i] = o;
}

// ------------------------------------------- cast + transpose weight (K=2048 rows)
// src: (2048 x ncols) fp32 row-major; dst: (ncols x 2048) bf16 row-major (dst may be offset)
__global__ __launch_bounds__(256) void transw_k(const float* __restrict__ src,
                                                unsigned short* __restrict__ dst,
                                                int ncols) {
  __shared__ unsigned short t[64][72];
  int n0 = blockIdx.x * 64, r0 = blockIdx.y * 64;
  int tid = threadIdx.x;
  int tx = tid & 15, ty = tid >> 4;
#pragma unroll
  for (int i = 0; i < 4; i++) {
    int r = ty * 4 + i;
    float4 v = *(const float4*)&src[(size_t)(r0 + r) * ncols + n0 + tx * 4];
    t[r][tx * 4 + 0] = f2bf(v.x);
    t[r][tx * 4 + 1] = f2bf(v.y);
    t[r][tx * 4 + 2] = f2bf(v.z);
    t[r][tx * 4 + 3] = f2bf(v.w);
  }
  __syncthreads();
  int nl = tid >> 2, seg = tid & 3;
  ushort8 o0, o1;
#pragma unroll
  for (int j = 0; j < 8; j++) {
    o0[j] = t[seg * 16 + j][nl];
    o1[j] = t[seg * 16 + 8 + j][nl];
  }
  size_t base = (size_t)(n0 + nl) * 2048 + r0 + seg * 16;
  *(ushort8*)&dst[base] = o0;
  *(ushort8*)&dst[base + 8] = o1;
}

// ---------------------------------------------------------------- GEMM (m97 structure)
// A: (BT x 2048) bf16 row-major.  Bt: (N x 2048) bf16 row-major (i.e. B^T).
// EPI 0: route to Q (BTx2048), K (BTx512), V^T (B,KVH,HD,T).  EPI 1: fp32 out (BTx2048).
template <int EPI>
__global__ __launch_bounds__(256) void gemm_k(const unsigned short* __restrict__ A,
                                              const unsigned short* __restrict__ Bt,
                                              unsigned short* __restrict__ q_out,
                                              unsigned short* __restrict__ k_out,
                                              unsigned short* __restrict__ v_out,
                                              float* __restrict__ f_out) {
  __shared__ unsigned short As[128 * 32];
  __shared__ unsigned short Bs[128 * 32];
  const int tid = threadIdx.x;
  const int lane = tid & 63;
  const int wid = tid >> 6;
  const int wr = wid >> 1, wc = wid & 1;
  const int row0 = blockIdx.x * 128, n00 = blockIdx.y * 128;
  const int lr = lane & 15, lk = (lane >> 4) * 8;
  const int c0 = tid, c1 = tid + 256;

  f32x4 acc[4][4] = {};

  for (int k0 = 0; k0 < 2048; k0 += 32) {
    __syncthreads();
    GLDS16(A + (size_t)(row0 + (c0 >> 2)) * 2048 + k0 + (c0 & 3) * 8, &As[c0 * 8]);
    GLDS16(A + (size_t)(row0 + (c1 >> 2)) * 2048 + k0 + (c1 & 3) * 8, &As[c1 * 8]);
    GLDS16(Bt + (size_t)(n00 + (c0 >> 2)) * 2048 + k0 + (c0 & 3) * 8, &Bs[c0 * 8]);
    GLDS16(Bt + (size_t)(n00 + (c1 >> 2)) * 2048 + k0 + (c1 & 3) * 8, &Bs[c1 * 8]);
    __syncthreads();
    bf16x8 af[4], bfr[4];
#pragma unroll
    for (int mi = 0; mi < 4; mi++)
      af[mi] = *(const bf16x8*)&As[(wr * 64 + mi * 16 + lr) * 32 + lk];
#pragma unroll
    for (int ni = 0; ni < 4; ni++)
      bfr[ni] = *(const bf16x8*)&Bs[(wc * 64 + ni * 16 + lr) * 32 + lk];
#pragma unroll
    for (int mi = 0; mi < 4; mi++)
#pragma unroll
      for (int ni = 0; ni < 4; ni++)
        acc[mi][ni] =
            __builtin_amdgcn_mfma_f32_16x16x32_bf16(af[mi], bfr[ni], acc[mi][ni], 0, 0, 0);
  }

  const int rbase = row0 + wr * 64;
  const int cbase = n00 + wc * 64;
#pragma unroll
  for (int mi = 0; mi < 4; mi++)
#pragma unroll
    for (int ni = 0; ni < 4; ni++)
#pragma unroll
      for (int r = 0; r < 4; r++) {
        int row = rbase + mi * 16 + (lane >> 4) * 4 + r;
        int col = cbase + ni * 16 + lr;
        float v = acc[mi][ni][r];
        if (EPI == 0) {
          if (col < 2048) {
            q_out[(size_t)row * 2048 + col] = f2bf(v);
          } else if (col < 2560) {
            k_out[(size_t)row * 512 + (col - 2048)] = f2bf(v);
          } else {
            int nv = col - 2560;
            int kvh = nv >> 7, d = nv & 127;
            int b = row >> 11, tt = row & 2047;
            v_out[((size_t)(b * NKVH + kvh) * HD + d) * T_SEQ + tt] = f2bf(v);
          }
        } else {
          f_out[(size_t)row * 2048 + col] = v;
        }
      }
}

// ---------------------------------------------------------------- RoPE (in-place, Q and K)
// one 64-lane wave handles one (row, head): lane i rotates pair (i, i+64)
__global__ __launch_bounds__(256) void rope_k(unsigned short* __restrict__ qb,
                                              unsigned short* __restrict__ kb) {
  int idx = blockIdx.x * 256 + threadIdx.x;
  int i = idx & 63;
  int wi = idx >> 6;
  int hh = wi % (NH + NKVH);
  int bt = wi / (NH + NKVH);
  int t = bt & (T_SEQ - 1);
  unsigned short* p = (hh < NH) ? (qb + (size_t)bt * 2048 + hh * HD)
                                : (kb + (size_t)bt * 512 + (hh - NH) * HD);
  // theta_i = 10000^(-i/64);  log2(10000) = 13.287712379549449
  float theta = exp2f(-(float)i * (13.287712379549449f / 64.0f));
  float ang = (float)t * theta;
  float s, c;
  sincosf(ang, &s, &c);
  float x1 = bf2f(p[i]), x2 = bf2f(p[i + 64]);
  p[i] = f2bf(x1 * c - x2 * s);
  p[i + 64] = f2bf(x1 * s + x2 * c);
}

// ---------------------------------------------------------------- flash attention
// grid: B*NH*(T/64) blocks, 256 threads = 4 waves; each wave owns a 16-row Q tile.
__global__ __launch_bounds__(256) void attn_k(const unsigned short* __restrict__ qb,
                                              const unsigned short* __restrict__ kb,
                                              const unsigned short* __restrict__ vt,
                                              unsigned short* __restrict__ ao) {
  __shared__ unsigned short pl[4][16][40];
  int bid = blockIdx.x;
  int qt = bid & 31;
  int h = (bid >> 5) & 15;
  int b = bid >> 9;
  int wid = threadIdx.x >> 6, lane = threadIdx.x & 63;
  int q0 = qt * 64 + wid * 16;
  int kvh = h >> 2;
  float slope = exp2f(-0.5f * (float)(h + 1));
  const int lr = lane & 15, lk = (lane >> 4) * 8;
  const int qrow_i = (lane >> 4) * 4;  // + r

  // Q fragments (A-operand): rows q0+lr, d = ks*32 + lk .. +8
  bf16x8 qf[4];
#pragma unroll
  for (int ks = 0; ks < 4; ks++)
    qf[ks] = *(const bf16x8*)&qb[((size_t)(b * T_SEQ + q0 + lr)) * 2048 + h * HD + ks * 32 + lk];

  const unsigned short* kbase = kb + (size_t)b * T_SEQ * 512 + kvh * HD;
  const unsigned short* vbase = vt + (size_t)(b * NKVH + kvh) * HD * T_SEQ;

  float m_st[4] = {-1e30f, -1e30f, -1e30f, -1e30f};
  float l_st[4] = {0.f, 0.f, 0.f, 0.f};
  f32x4 oacc[8] = {};

  const int q_hi = q0 + 15;
  for (int k0 = 0; k0 <= q_hi; k0 += 32) {
    // K fragments (B-operand): key = k0 + nt*16 + lr, d = ks*32 + lk .. +8
    bf16x8 kf[2][4];
#pragma unroll
    for (int nt = 0; nt < 2; nt++)
#pragma unroll
      for (int ks = 0; ks < 4; ks++)
        kf[nt][ks] =
            *(const bf16x8*)&kbase[(size_t)(k0 + nt * 16 + lr) * 512 + ks * 32 + lk];

    f32x4 sc0 = {0.f, 0.f, 0.f, 0.f}, sc1 = {0.f, 0.f, 0.f, 0.f};
#pragma unroll
    for (int ks = 0; ks < 4; ks++) {
      sc0 = __builtin_amdgcn_mfma_f32_16x16x32_bf16(qf[ks], kf[0][ks], sc0, 0, 0, 0);
      sc1 = __builtin_amdgcn_mfma_f32_16x16x32_bf16(qf[ks], kf[1][ks], sc1, 0, 0, 0);
    }

    // scores + online softmax. C layout: col(key)=lane&15, row(q)=(lane>>4)*4+r
#pragma unroll
    for (int r = 0; r < 4; r++) {
      int q = q0 + qrow_i + r;
      int key0 = k0 + lr, key1 = k0 + 16 + lr;
      float s0 = sc0[r] * ATT_SCALE + slope * (float)(key0 - q);
      if (key0 > q) s0 = -1e30f;
      float s1 = sc1[r] * ATT_SCALE + slope * (float)(key1 - q);
      if (key1 > q) s1 = -1e30f;
      float mx = fmaxf(s0, s1);
#pragma unroll
      for (int m = 1; m < 16; m <<= 1) mx = fmaxf(mx, __shfl_xor(mx, m));
      float mnew = fmaxf(m_st[r], mx);
      float corr = __expf(m_st[r] - mnew);
      float p0 = __expf(s0 - mnew);
      float p1 = __expf(s1 - mnew);
      float rs = p0 + p1;
#pragma unroll
      for (int m = 1; m < 16; m <<= 1) rs += __shfl_xor(rs, m);
      l_st[r] = l_st[r] * corr + rs;
      m_st[r] = mnew;
      pl[wid][qrow_i + r][lr] = f2bf(p0);
      pl[wid][qrow_i + r][16 + lr] = f2bf(p1);
#pragma unroll
      for (int dt = 0; dt < 8; dt++) oacc[dt][r] *= corr;
    }
    asm volatile("s_waitcnt lgkmcnt(0)" ::: "memory");
    // P as A-operand: row(q)=lr, k(key)=lk..+8
    bf16x8 pf = *(const bf16x8*)&pl[wid][lr][lk];
    // V^T fragments (B-operand): d = dt*16 + lr, key = k0 + lk .. +8
#pragma unroll
    for (int dt = 0; dt < 8; dt++) {
      bf16x8 vf = *(const bf16x8*)&vbase[(size_t)(dt * 16 + lr) * T_SEQ + k0 + lk];
      oacc[dt] = __builtin_amdgcn_mfma_f32_16x16x32_bf16(pf, vf, oacc[dt], 0, 0, 0);
    }
  }

  // epilogue: ao[bt][h*128 + d] bf16
#pragma unroll
  for (int dt = 0; dt < 8; dt++)
#pragma unroll
    for (int r = 0; r < 4; r++) {
      int q = q0 + qrow_i + r;
      float v = oacc[dt][r] / l_st[r];
      ao[((size_t)(b * T_SEQ + q)) * 2048 + h * HD + dt * 16 + lr] = f2bf(v);
    }
}

// ---------------------------------------------------------------- launch
extern "C" void kernel_launch(void* const* d_in, const int* in_sizes, int n_in,
                              void* d_out, int out_size, void* d_ws, size_t ws_size,
                              hipStream_t stream) {
  const float* x = (const float*)d_in[0];
  const float* Wq = (const float*)d_in[1];
  const float* Wk = (const float*)d_in[2];
  const float* Wv = (const float*)d_in[3];
  const float* Wo = (const float*)d_in[4];

  char* w = (char*)d_ws;
  // region0: x_bf16 (33.5MB), later reused as attention output
  unsigned short* xb = (unsigned short*)w;
  // region1: W_qkv^T (12.6MB), later reused for Wo^T
  unsigned short* wqt = (unsigned short*)(w + 33554432);
  unsigned short* qb = (unsigned short*)(w + 33554432 + 12582912);
  unsigned short* kb = (unsigned short*)(w + 33554432 + 12582912 + 33554432);
  unsigned short* vtb = (unsigned short*)(w + 33554432 + 12582912 + 33554432 + 8388608);
  // total: 96,468,992 bytes

  castx_k<<<16384, 256, 0, stream>>>(x, xb);
  transw_k<<<dim3(32, 32), 256, 0, stream>>>(Wq, wqt, 2048);
  transw_k<<<dim3(8, 32), 256, 0, stream>>>(Wk, wqt + (size_t)2048 * 2048, 512);
  transw_k<<<dim3(8, 32), 256, 0, stream>>>(Wv, wqt + (size_t)2560 * 2048, 512);
  gemm_k<0><<<dim3(64, 24), 256, 0, stream>>>(xb, wqt, qb, kb, vtb, nullptr);
  rope_k<<<40960, 256, 0, stream>>>(qb, kb);
  // Wo^T into the (now free) wqt region; ordered after gemm_k<0> on the stream
  transw_k<<<dim3(32, 32), 256, 0, stream>>>(Wo, wqt, 2048);
  attn_k<<<2048, 256, 0, stream>>>(qb, kb, vtb, xb);
  gemm_k<1><<<dim3(64, 16), 256, 0, stream>>>(xb, wqt, nullptr, nullptr, nullptr,
                                              (float*)d_out);
}

// Round 2
// 722.982 us; speedup vs baseline: 1.6014x; 1.6014x over previous
//
#include <hip/hip_runtime.h>
#include <hip/hip_bf16.h>
#include <stdint.h>

// Problem constants
#define T_SEQ 2048
#define DM    2048
#define NH    16
#define NKVH  4
#define HD    128
#define NBATCH 4
#define BT    (NBATCH * T_SEQ)   // 8192 rows of x
#define ATT_SCALE 0.08838834764831845f  // 1/sqrt(128)
#define LOG2E 1.4426950408889634f

typedef __attribute__((ext_vector_type(8))) short bf16x8;
typedef __attribute__((ext_vector_type(4))) float f32x4;
typedef __attribute__((ext_vector_type(16))) float f32x16;
typedef __attribute__((ext_vector_type(8))) unsigned short ushort8;
typedef __attribute__((ext_vector_type(4))) unsigned short ushort4v;

static __device__ __forceinline__ unsigned short f2bf(float f) {
  __hip_bfloat16 h = __float2bfloat16(f);
  return __builtin_bit_cast(unsigned short, h);
}
static __device__ __forceinline__ float bf2f(unsigned short u) {
  unsigned int v = ((unsigned int)u) << 16;
  return __builtin_bit_cast(float, v);
}
static __device__ __forceinline__ unsigned int packbf2(float a, float b) {
  return (unsigned int)f2bf(a) | ((unsigned int)f2bf(b) << 16);
}

#define GLDS16(g, l)                                                        \
  __builtin_amdgcn_global_load_lds(                                         \
      (const __attribute__((address_space(1))) void*)(g),                   \
      (__attribute__((address_space(3))) void*)(l), 16, 0, 0)

// ---------------------------------------------------------------- cast x
__global__ __launch_bounds__(256) void castx_k(const float* __restrict__ x,
                                               unsigned short* __restrict__ xb) {
  int i = (blockIdx.x * 256 + threadIdx.x) * 4;
  float4 v = *(const float4*)&x[i];
  ushort4v o;
  o[0] = f2bf(v.x); o[1] = f2bf(v.y); o[2] = f2bf(v.z); o[3] = f2bf(v.w);
  *(ushort4v*)&xb[i] = o;
}

// ------------------------------------------- cast + transpose weight (K=2048 rows)
__global__ __launch_bounds__(256) void transw_k(const float* __restrict__ src,
                                                unsigned short* __restrict__ dst,
                                                int ncols) {
  __shared__ unsigned short t[64][72];
  int n0 = blockIdx.x * 64, r0 = blockIdx.y * 64;
  int tid = threadIdx.x;
  int tx = tid & 15, ty = tid >> 4;
#pragma unroll
  for (int i = 0; i < 4; i++) {
    int r = ty * 4 + i;
    float4 v = *(const float4*)&src[(size_t)(r0 + r) * ncols + n0 + tx * 4];
    t[r][tx * 4 + 0] = f2bf(v.x);
    t[r][tx * 4 + 1] = f2bf(v.y);
    t[r][tx * 4 + 2] = f2bf(v.z);
    t[r][tx * 4 + 3] = f2bf(v.w);
  }
  __syncthreads();
  int nl = tid >> 2, seg = tid & 3;
  ushort8 o0, o1;
#pragma unroll
  for (int j = 0; j < 8; j++) {
    o0[j] = t[seg * 16 + j][nl];
    o1[j] = t[seg * 16 + 8 + j][nl];
  }
  size_t base = (size_t)(n0 + nl) * 2048 + r0 + seg * 16;
  *(ushort8*)&dst[base] = o0;
  *(ushort8*)&dst[base + 8] = o1;
}

// ---------------------------------------------------------------- GEMM (m97 structure)
template <int EPI>
__global__ __launch_bounds__(256) void gemm_k(const unsigned short* __restrict__ A,
                                              const unsigned short* __restrict__ Bt,
                                              unsigned short* __restrict__ q_out,
                                              unsigned short* __restrict__ k_out,
                                              unsigned short* __restrict__ v_out,
                                              float* __restrict__ f_out) {
  __shared__ unsigned short As[128 * 32];
  __shared__ unsigned short Bs[128 * 32];
  const int tid = threadIdx.x;
  const int lane = tid & 63;
  const int wid = tid >> 6;
  const int wr = wid >> 1, wc = wid & 1;
  const int row0 = blockIdx.x * 128, n00 = blockIdx.y * 128;
  const int lr = lane & 15, lk = (lane >> 4) * 8;
  const int c0 = tid, c1 = tid + 256;

  f32x4 acc[4][4] = {};

  for (int k0 = 0; k0 < 2048; k0 += 32) {
    __syncthreads();
    GLDS16(A + (size_t)(row0 + (c0 >> 2)) * 2048 + k0 + (c0 & 3) * 8, &As[c0 * 8]);
    GLDS16(A + (size_t)(row0 + (c1 >> 2)) * 2048 + k0 + (c1 & 3) * 8, &As[c1 * 8]);
    GLDS16(Bt + (size_t)(n00 + (c0 >> 2)) * 2048 + k0 + (c0 & 3) * 8, &Bs[c0 * 8]);
    GLDS16(Bt + (size_t)(n00 + (c1 >> 2)) * 2048 + k0 + (c1 & 3) * 8, &Bs[c1 * 8]);
    __syncthreads();
    bf16x8 af[4], bfr[4];
#pragma unroll
    for (int mi = 0; mi < 4; mi++)
      af[mi] = *(const bf16x8*)&As[(wr * 64 + mi * 16 + lr) * 32 + lk];
#pragma unroll
    for (int ni = 0; ni < 4; ni++)
      bfr[ni] = *(const bf16x8*)&Bs[(wc * 64 + ni * 16 + lr) * 32 + lk];
#pragma unroll
    for (int mi = 0; mi < 4; mi++)
#pragma unroll
      for (int ni = 0; ni < 4; ni++)
        acc[mi][ni] =
            __builtin_amdgcn_mfma_f32_16x16x32_bf16(af[mi], bfr[ni], acc[mi][ni], 0, 0, 0);
  }

  const int rbase = row0 + wr * 64;
  const int cbase = n00 + wc * 64;
#pragma unroll
  for (int mi = 0; mi < 4; mi++)
#pragma unroll
    for (int ni = 0; ni < 4; ni++)
#pragma unroll
      for (int r = 0; r < 4; r++) {
        int row = rbase + mi * 16 + (lane >> 4) * 4 + r;
        int col = cbase + ni * 16 + lr;
        float v = acc[mi][ni][r];
        if (EPI == 0) {
          if (col < 2048) {
            q_out[(size_t)row * 2048 + col] = f2bf(v);
          } else if (col < 2560) {
            k_out[(size_t)row * 512 + (col - 2048)] = f2bf(v);
          } else {
            int nv = col - 2560;
            int kvh = nv >> 7, d = nv & 127;
            int b = row >> 11, tt = row & 2047;
            v_out[((size_t)(b * NKVH + kvh) * HD + d) * T_SEQ + tt] = f2bf(v);
          }
        } else {
          f_out[(size_t)row * 2048 + col] = v;
        }
      }
}

// ---------------------------------------------------------------- RoPE (in-place, Q and K)
__global__ __launch_bounds__(256) void rope_k(unsigned short* __restrict__ qb,
                                              unsigned short* __restrict__ kb) {
  int idx = blockIdx.x * 256 + threadIdx.x;
  int i = idx & 63;
  int wi = idx >> 6;
  int hh = wi % (NH + NKVH);
  int bt = wi / (NH + NKVH);
  int t = bt & (T_SEQ - 1);
  unsigned short* p = (hh < NH) ? (qb + (size_t)bt * 2048 + hh * HD)
                                : (kb + (size_t)bt * 512 + (hh - NH) * HD);
  float theta = exp2f(-(float)i * (13.287712379549449f / 64.0f));
  float ang = (float)t * theta;
  float s, c;
  sincosf(ang, &s, &c);
  float x1 = bf2f(p[i]), x2 = bf2f(p[i + 64]);
  p[i] = f2bf(x1 * c - x2 * s);
  p[i + 64] = f2bf(x1 * s + x2 * c);
}

// ---------------------------------------------------------------- flash attention
// Swapped-operand 32x32 structure: each wave owns 32 q-rows of one (b,h).
// QK^T computed as mfma(K, Q) -> S^T (q along lanes); PV as mfma(V^T, P) -> O^T.
// Softmax state per-lane scalar; 1 cross-lane shuffle per reduce.
// grid: B*NH*(T/128) blocks, 256 threads = 4 waves.
__global__ __launch_bounds__(256) void attn_k(const unsigned short* __restrict__ qb,
                                              const unsigned short* __restrict__ kb,
                                              const unsigned short* __restrict__ vt,
                                              unsigned short* __restrict__ ao) {
  __shared__ __align__(16) unsigned short ot[4][32][136];
  const int bid = blockIdx.x;
  const int qt = bid & 15;
  const int h = (bid >> 4) & 15;
  const int b = bid >> 8;
  const int wid = threadIdx.x >> 6, lane = threadIdx.x & 63;
  const int l31 = lane & 31, lh = lane >> 5;
  const int q0 = qt * 128 + wid * 32;
  const int kvh = h >> 2;
  const float slope2 = exp2f(-0.5f * (float)(h + 1)) * LOG2E;
  const float scale2 = ATT_SCALE * LOG2E;

  // Q fragments (B-operand of swapped QK^T): col(q)=lane&31, k(d)=lh*8+j
  const unsigned short* qrow =
      qb + ((size_t)(b * T_SEQ + q0 + l31)) * 2048 + h * HD + lh * 8;
  bf16x8 qf[8];
#pragma unroll
  for (int ds = 0; ds < 8; ds++) qf[ds] = *(const bf16x8*)&qrow[ds * 16];

  const unsigned short* kbase = kb + (size_t)b * T_SEQ * 512 + kvh * HD + lh * 8;
  const unsigned short* vbase =
      vt + (size_t)(b * NKVH + kvh) * HD * T_SEQ + (size_t)l31 * T_SEQ + lh * 8;

  f32x16 oacc[4] = {};
  float m2 = -1e30f, l_sum = 0.f;

  const int nt = q0 / 32 + 1;

  // prologue: K fragments for tile 0 (A-operand: row(key)=lane&31, k(d)=lh*8+j)
  bf16x8 kf[8];
  {
    const unsigned short* kp = kbase + (size_t)l31 * 512;
#pragma unroll
    for (int ds = 0; ds < 8; ds++) kf[ds] = *(const bf16x8*)&kp[ds * 16];
  }

#pragma unroll 1
  for (int t = 0; t < nt; t++) {
    const int k0 = t * 32;

    // QK^T: two independent accumulation chains
    f32x16 sca = 0.f, scb = 0.f;
#pragma unroll
    for (int ds = 0; ds < 4; ds++)
      sca = __builtin_amdgcn_mfma_f32_32x32x16_bf16(kf[ds], qf[ds], sca, 0, 0, 0);
#pragma unroll
    for (int ds = 4; ds < 8; ds++)
      scb = __builtin_amdgcn_mfma_f32_32x32x16_bf16(kf[ds], qf[ds], scb, 0, 0, 0);

    // V fragments for this tile (A-operand of PV: row(d)=lane&31, k(key)=lh*8+j)
    bf16x8 vf[4][2];
#pragma unroll
    for (int dt = 0; dt < 4; dt++)
#pragma unroll
      for (int ks = 0; ks < 2; ks++)
        vf[dt][ks] = *(const bf16x8*)&vbase[(size_t)dt * 32 * T_SEQ + k0 + ks * 16];

    // prefetch K fragments for next tile
    {
      const int k0n = (t + 1 < nt) ? (k0 + 32) : k0;
      const unsigned short* kp = kbase + (size_t)(k0n + l31) * 512;
#pragma unroll
      for (int ds = 0; ds < 8; ds++) kf[ds] = *(const bf16x8*)&kp[ds * 16];
    }

    // scores (base-2 domain). key = k0 + crow(r,lh), q = q0 + l31.
    // per-row ALiBi constant -slope*q dropped (softmax invariant).
    float s[16];
    const float ab = slope2 * (float)k0;
    const bool last = (t == nt - 1);
#pragma unroll
    for (int r = 0; r < 16; r++) {
      const int crow = (r & 3) + 8 * (r >> 2) + 4 * lh;
      float v = fmaf(sca[r] + scb[r], scale2, fmaf(slope2, (float)crow, ab));
      if (last && crow > l31) v = -1e30f;
      s[r] = v;
    }

    // max tree (16 -> 1) + cross-half
    float t8[8], t4[4];
#pragma unroll
    for (int i = 0; i < 8; i++) t8[i] = fmaxf(s[i], s[i + 8]);
#pragma unroll
    for (int i = 0; i < 4; i++) t4[i] = fmaxf(t8[i], t8[i + 4]);
    float mx = fmaxf(fmaxf(t4[0], t4[1]), fmaxf(t4[2], t4[3]));
    mx = fmaxf(mx, __shfl_xor(mx, 32));
    const float m2new = fmaxf(m2, mx);
    const float corr = exp2f(m2 - m2new);

    float p[16];
#pragma unroll
    for (int r = 0; r < 16; r++) p[r] = exp2f(s[r] - m2new);

    float a8[8], a4[4];
#pragma unroll
    for (int i = 0; i < 8; i++) a8[i] = p[i] + p[i + 8];
#pragma unroll
    for (int i = 0; i < 4; i++) a4[i] = a8[i] + a8[i + 4];
    float rs = (a4[0] + a4[1]) + (a4[2] + a4[3]);
    rs += __shfl_xor(rs, 32);
    l_sum = l_sum * corr + rs;
    m2 = m2new;

#pragma unroll
    for (int dt = 0; dt < 4; dt++) oacc[dt] *= corr;

    // pack P to bf16 pairs and redistribute to B-fragment layout
    unsigned int w[8];
#pragma unroll
    for (int i = 0; i < 8; i++) w[i] = packbf2(p[2 * i], p[2 * i + 1]);
    const unsigned int ta = __shfl_xor(lh ? w[0] : w[2], 32);
    const unsigned int tb = __shfl_xor(lh ? w[1] : w[3], 32);
    const unsigned int tc = __shfl_xor(lh ? w[4] : w[6], 32);
    const unsigned int td = __shfl_xor(lh ? w[5] : w[7], 32);
    union U4 { unsigned int u[4]; bf16x8 v; } f0, f1;
    f0.u[0] = lh ? ta : w[0];
    f0.u[1] = lh ? tb : w[1];
    f0.u[2] = lh ? w[2] : ta;
    f0.u[3] = lh ? w[3] : tb;
    f1.u[0] = lh ? tc : w[4];
    f1.u[1] = lh ? td : w[5];
    f1.u[2] = lh ? w[6] : tc;
    f1.u[3] = lh ? w[7] : td;

    // PV: oacc[dt] += V^T[dtile] * P
#pragma unroll
    for (int dt = 0; dt < 4; dt++) {
      oacc[dt] = __builtin_amdgcn_mfma_f32_32x32x16_bf16(vf[dt][0], f0.v, oacc[dt], 0, 0, 0);
      oacc[dt] = __builtin_amdgcn_mfma_f32_32x32x16_bf16(vf[dt][1], f1.v, oacc[dt], 0, 0, 0);
    }
  }

  // epilogue: O^T (q along lanes, d along regs) -> LDS transpose -> coalesced store
  const float inv = 1.0f / l_sum;
#pragma unroll
  for (int dt = 0; dt < 4; dt++)
#pragma unroll
    for (int rg = 0; rg < 4; rg++) {
      ushort4v o;
#pragma unroll
      for (int j = 0; j < 4; j++) o[j] = f2bf(oacc[dt][rg * 4 + j] * inv);
      *(ushort4v*)&ot[wid][l31][dt * 32 + rg * 8 + lh * 4] = o;
    }
  __syncthreads();
  const int rrow = lane >> 4, chunk = lane & 15;
#pragma unroll
  for (int ps = 0; ps < 8; ps++) {
    const int row = ps * 4 + rrow;
    ushort8 v = *(const ushort8*)&ot[wid][row][chunk * 8];
    *(ushort8*)&ao[((size_t)(b * T_SEQ + q0 + row)) * 2048 + h * HD + chunk * 8] = v;
  }
}

// ---------------------------------------------------------------- launch
extern "C" void kernel_launch(void* const* d_in, const int* in_sizes, int n_in,
                              void* d_out, int out_size, void* d_ws, size_t ws_size,
                              hipStream_t stream) {
  const float* x = (const float*)d_in[0];
  const float* Wq = (const float*)d_in[1];
  const float* Wk = (const float*)d_in[2];
  const float* Wv = (const float*)d_in[3];
  const float* Wo = (const float*)d_in[4];

  char* w = (char*)d_ws;
  unsigned short* xb = (unsigned short*)w;                       // 33.5MB, reused for attn out
  unsigned short* wqt = (unsigned short*)(w + 33554432);         // 12.6MB, reused for Wo^T
  unsigned short* qb = (unsigned short*)(w + 33554432 + 12582912);
  unsigned short* kb = (unsigned short*)(w + 33554432 + 12582912 + 33554432);
  unsigned short* vtb = (unsigned short*)(w + 33554432 + 12582912 + 33554432 + 8388608);

  castx_k<<<16384, 256, 0, stream>>>(x, xb);
  transw_k<<<dim3(32, 32), 256, 0, stream>>>(Wq, wqt, 2048);
  transw_k<<<dim3(8, 32), 256, 0, stream>>>(Wk, wqt + (size_t)2048 * 2048, 512);
  transw_k<<<dim3(8, 32), 256, 0, stream>>>(Wv, wqt + (size_t)2560 * 2048, 512);
  gemm_k<0><<<dim3(64, 24), 256, 0, stream>>>(xb, wqt, qb, kb, vtb, nullptr);
  rope_k<<<40960, 256, 0, stream>>>(qb, kb);
  transw_k<<<dim3(32, 32), 256, 0, stream>>>(Wo, wqt, 2048);
  attn_k<<<1024, 256, 0, stream>>>(qb, kb, vtb, xb);
  gemm_k<1><<<dim3(64, 16), 256, 0, stream>>>(xb, wqt, nullptr, nullptr, nullptr,
                                              (float*)d_out);
}

// Round 3
// 525.890 us; speedup vs baseline: 2.2016x; 1.3748x over previous
//
#include <hip/hip_runtime.h>
#include <hip/hip_bf16.h>
#include <stdint.h>

// Problem constants
#define T_SEQ 2048
#define DM    2048
#define NH    16
#define NKVH  4
#define HD    128
#define NBATCH 4
#define BT    (NBATCH * T_SEQ)   // 8192 rows of x
#define ATT_SCALE 0.08838834764831845f  // 1/sqrt(128)
#define LOG2E 1.4426950408889634f

typedef __attribute__((ext_vector_type(8))) short bf16x8;
typedef __attribute__((ext_vector_type(4))) float f32x4;
typedef __attribute__((ext_vector_type(16))) float f32x16;
typedef __attribute__((ext_vector_type(8))) unsigned short ushort8;
typedef __attribute__((ext_vector_type(4))) unsigned short ushort4v;

static __device__ __forceinline__ unsigned short f2bf(float f) {
  __hip_bfloat16 h = __float2bfloat16(f);
  return __builtin_bit_cast(unsigned short, h);
}
static __device__ __forceinline__ float bf2f(unsigned short u) {
  unsigned int v = ((unsigned int)u) << 16;
  return __builtin_bit_cast(float, v);
}
static __device__ __forceinline__ unsigned int packbf2(float a, float b) {
  return (unsigned int)f2bf(a) | ((unsigned int)f2bf(b) << 16);
}

#define GLDS16(g, l)                                                        \
  __builtin_amdgcn_global_load_lds(                                         \
      (const __attribute__((address_space(1))) void*)(g),                   \
      (__attribute__((address_space(3))) void*)(l), 16, 0, 0)

// ---------------------------------------------------------------- cast x
__global__ __launch_bounds__(256) void castx_k(const float* __restrict__ x,
                                               unsigned short* __restrict__ xb) {
  int i = (blockIdx.x * 256 + threadIdx.x) * 4;
  float4 v = *(const float4*)&x[i];
  ushort4v o;
  o[0] = f2bf(v.x); o[1] = f2bf(v.y); o[2] = f2bf(v.z); o[3] = f2bf(v.w);
  *(ushort4v*)&xb[i] = o;
}

// ------------------------------------------- cast + transpose weight (K=2048 rows)
__global__ __launch_bounds__(256) void transw_k(const float* __restrict__ src,
                                                unsigned short* __restrict__ dst,
                                                int ncols) {
  __shared__ unsigned short t[64][72];
  int n0 = blockIdx.x * 64, r0 = blockIdx.y * 64;
  int tid = threadIdx.x;
  int tx = tid & 15, ty = tid >> 4;
#pragma unroll
  for (int i = 0; i < 4; i++) {
    int r = ty * 4 + i;
    float4 v = *(const float4*)&src[(size_t)(r0 + r) * ncols + n0 + tx * 4];
    t[r][tx * 4 + 0] = f2bf(v.x);
    t[r][tx * 4 + 1] = f2bf(v.y);
    t[r][tx * 4 + 2] = f2bf(v.z);
    t[r][tx * 4 + 3] = f2bf(v.w);
  }
  __syncthreads();
  int nl = tid >> 2, seg = tid & 3;
  ushort8 o0, o1;
#pragma unroll
  for (int j = 0; j < 8; j++) {
    o0[j] = t[seg * 16 + j][nl];
    o1[j] = t[seg * 16 + 8 + j][nl];
  }
  size_t base = (size_t)(n0 + nl) * 2048 + r0 + seg * 16;
  *(ushort8*)&dst[base] = o0;
  *(ushort8*)&dst[base + 8] = o1;
}

// ---------------------------------------------------------------- GEMM (m97 structure)
template <int EPI>
__global__ __launch_bounds__(256) void gemm_k(const unsigned short* __restrict__ A,
                                              const unsigned short* __restrict__ Bt,
                                              unsigned short* __restrict__ q_out,
                                              unsigned short* __restrict__ k_out,
                                              unsigned short* __restrict__ v_out,
                                              float* __restrict__ f_out) {
  __shared__ unsigned short As[128 * 32];
  __shared__ unsigned short Bs[128 * 32];
  const int tid = threadIdx.x;
  const int lane = tid & 63;
  const int wid = tid >> 6;
  const int wr = wid >> 1, wc = wid & 1;
  const int row0 = blockIdx.x * 128, n00 = blockIdx.y * 128;
  const int lr = lane & 15, lk = (lane >> 4) * 8;
  const int c0 = tid, c1 = tid + 256;

  f32x4 acc[4][4] = {};

  for (int k0 = 0; k0 < 2048; k0 += 32) {
    __syncthreads();
    GLDS16(A + (size_t)(row0 + (c0 >> 2)) * 2048 + k0 + (c0 & 3) * 8, &As[c0 * 8]);
    GLDS16(A + (size_t)(row0 + (c1 >> 2)) * 2048 + k0 + (c1 & 3) * 8, &As[c1 * 8]);
    GLDS16(Bt + (size_t)(n00 + (c0 >> 2)) * 2048 + k0 + (c0 & 3) * 8, &Bs[c0 * 8]);
    GLDS16(Bt + (size_t)(n00 + (c1 >> 2)) * 2048 + k0 + (c1 & 3) * 8, &Bs[c1 * 8]);
    __syncthreads();
    bf16x8 af[4], bfr[4];
#pragma unroll
    for (int mi = 0; mi < 4; mi++)
      af[mi] = *(const bf16x8*)&As[(wr * 64 + mi * 16 + lr) * 32 + lk];
#pragma unroll
    for (int ni = 0; ni < 4; ni++)
      bfr[ni] = *(const bf16x8*)&Bs[(wc * 64 + ni * 16 + lr) * 32 + lk];
#pragma unroll
    for (int mi = 0; mi < 4; mi++)
#pragma unroll
      for (int ni = 0; ni < 4; ni++)
        acc[mi][ni] =
            __builtin_amdgcn_mfma_f32_16x16x32_bf16(af[mi], bfr[ni], acc[mi][ni], 0, 0, 0);
  }

  const int rbase = row0 + wr * 64;
  const int cbase = n00 + wc * 64;
#pragma unroll
  for (int mi = 0; mi < 4; mi++)
#pragma unroll
    for (int ni = 0; ni < 4; ni++)
#pragma unroll
      for (int r = 0; r < 4; r++) {
        int row = rbase + mi * 16 + (lane >> 4) * 4 + r;
        int col = cbase + ni * 16 + lr;
        float v = acc[mi][ni][r];
        if (EPI == 0) {
          if (col < 2048) {
            q_out[(size_t)row * 2048 + col] = f2bf(v);
          } else if (col < 2560) {
            k_out[(size_t)row * 512 + (col - 2048)] = f2bf(v);
          } else {
            int nv = col - 2560;
            int kvh = nv >> 7, d = nv & 127;
            int b = row >> 11, tt = row & 2047;
            v_out[((size_t)(b * NKVH + kvh) * HD + d) * T_SEQ + tt] = f2bf(v);
          }
        } else {
          f_out[(size_t)row * 2048 + col] = v;
        }
      }
}

// ---------------------------------------------------------------- RoPE (in-place, Q and K)
__global__ __launch_bounds__(256) void rope_k(unsigned short* __restrict__ qb,
                                              unsigned short* __restrict__ kb) {
  int idx = blockIdx.x * 256 + threadIdx.x;
  int i = idx & 63;
  int wi = idx >> 6;
  int hh = wi % (NH + NKVH);
  int bt = wi / (NH + NKVH);
  int t = bt & (T_SEQ - 1);
  unsigned short* p = (hh < NH) ? (qb + (size_t)bt * 2048 + hh * HD)
                                : (kb + (size_t)bt * 512 + (hh - NH) * HD);
  float theta = exp2f(-(float)i * (13.287712379549449f / 64.0f));
  float ang = (float)t * theta;
  float s, c;
  sincosf(ang, &s, &c);
  float x1 = bf2f(p[i]), x2 = bf2f(p[i + 64]);
  p[i] = f2bf(x1 * c - x2 * s);
  p[i + 64] = f2bf(x1 * s + x2 * c);
}

// ---------------------------------------------------------------- flash attention
// Balanced causal pairing: block handles q-tiles j=p and 15-p (uniform 68 iters).
// K/V staged per-block in LDS via global_load_lds (coalesced), XOR-swizzled for
// conflict-free ds_read_b128. Swapped-operand 32x32 MFMA, in-register softmax.
// grid: B*NH*8 = 512 blocks, 256 threads = 4 waves, 32 q-rows/wave.
__global__ __launch_bounds__(256) void attn_k(const unsigned short* __restrict__ qb,
                                              const unsigned short* __restrict__ kb,
                                              const unsigned short* __restrict__ vt,
                                              unsigned short* __restrict__ ao) {
  // LDS: K dbuf [2][32][128] @ 0..8191, V^T dbuf [2][128][32] @ 8192..16383 (shorts)
  // epilogue tile ot[4][32][136] overlays the whole thing (barrier-separated)
  __shared__ __align__(16) unsigned short smem[17408];

  const int bid = blockIdx.x;
  const int p = bid & 7;
  const int h = (bid >> 3) & 15;
  const int b = bid >> 7;
  const int tid = threadIdx.x;
  const int wid = tid >> 6, lane = tid & 63;
  const int l31 = lane & 31, lh = lane >> 5;
  const int kvh = h >> 2;
  const float slope2 = exp2f(-0.5f * (float)(h + 1)) * LOG2E;
  const float scale2 = ATT_SCALE * LOG2E;

  // staging address constants
  const int krow = tid >> 4;                 // 0..15  (K: 16 rows per 4KB call)
  const int kchunk = tid & 15;
  const int cgk = kchunk ^ (krow & 7);       // inverse swizzle on global source
  const int vrow = tid >> 2;                 // 0..63  (V: 64 rows per 4KB call)
  const int vchunk = tid & 3;
  const int cgv = vchunk ^ (vrow & 3);
  const int kxor = l31 & 7;                  // read-side swizzle
  const int vxor = l31 & 3;

  const unsigned short* khead = kb + (size_t)(b * T_SEQ) * 512 + kvh * 128;
  const unsigned short* vhead = vt + (size_t)(b * NKVH + kvh) * HD * T_SEQ;

  auto stage = [&](int buf, int k0) {
    // K tile: 32 rows x 256B, swizzled source
#pragma unroll
    for (int c = 0; c < 2; c++)
      GLDS16(khead + (size_t)(k0 + c * 16 + krow) * 512 + cgk * 8,
             &smem[buf * 4096 + c * 2048 + tid * 8]);
    // V^T tile: 128 rows x 64B, swizzled source
#pragma unroll
    for (int c = 0; c < 2; c++)
      GLDS16(vhead + (size_t)(c * 64 + vrow) * T_SEQ + k0 + cgv * 8,
             &smem[8192 + buf * 4096 + c * 2048 + tid * 8]);
  };

  unsigned short (*ot)[32][136] = (unsigned short(*)[32][136])smem;

#pragma unroll 1
  for (int half = 0; half < 2; ++half) {
    const int j = half ? (15 - p) : p;
    const int q0 = j * 128 + wid * 32;
    const int dt_w = j * 4 + wid;   // this wave's diagonal tile
    const int T_blk = j * 4 + 4;    // tiles the block iterates

    // Q fragments (B-operand): col(q)=l31, k(d)=lh*8+j
    const unsigned short* qrow =
        qb + ((size_t)(b * T_SEQ + q0 + l31)) * 2048 + h * HD + lh * 8;
    bf16x8 qf[8];
#pragma unroll
    for (int ds = 0; ds < 8; ds++) qf[ds] = *(const bf16x8*)&qrow[ds * 16];

    f32x16 oacc[4] = {};
    float m2 = -1e30f, l_sum = 0.f;

    __syncthreads();          // previous epilogue's LDS reads complete
    stage(0, 0);
    __syncthreads();          // staging drained (compiler emits vmcnt(0))
    int cur = 0;

#pragma unroll 1
    for (int t = 0; t < T_blk; ++t) {
      if (t + 1 < T_blk) stage(cur ^ 1, 32 * (t + 1));

      if (t <= dt_w) {
        const int k0 = t * 32;
        const unsigned short* Kb = &smem[cur * 4096];
        const unsigned short* Vb = &smem[8192 + cur * 4096];

        // K fragments (A-operand): row(key)=l31, chunk=2ds+lh, swizzled
        bf16x8 kf[8];
#pragma unroll
        for (int ds = 0; ds < 8; ds++)
          kf[ds] = *(const bf16x8*)&Kb[l31 * 128 + ((2 * ds + lh) ^ kxor) * 8];
        // V fragments (A-operand): row(d)=dt*32+l31, chunk=2ks+lh, swizzled
        bf16x8 vf[4][2];
#pragma unroll
        for (int dt = 0; dt < 4; dt++)
#pragma unroll
          for (int ks = 0; ks < 2; ks++)
            vf[dt][ks] =
                *(const bf16x8*)&Vb[(dt * 32 + l31) * 32 + ((2 * ks + lh) ^ vxor) * 8];

        __builtin_amdgcn_s_setprio(1);
        f32x16 sca = 0.f, scb = 0.f;
#pragma unroll
        for (int ds = 0; ds < 4; ds++)
          sca = __builtin_amdgcn_mfma_f32_32x32x16_bf16(kf[ds], qf[ds], sca, 0, 0, 0);
#pragma unroll
        for (int ds = 4; ds < 8; ds++)
          scb = __builtin_amdgcn_mfma_f32_32x32x16_bf16(kf[ds], qf[ds], scb, 0, 0, 0);
        __builtin_amdgcn_s_setprio(0);

        // scores (base-2). key = k0 + crow, q = q0 + l31
        float s[16];
        const float ab = slope2 * (float)k0;
        const bool diag = (t == dt_w);
#pragma unroll
        for (int r = 0; r < 16; r++) {
          const int crow = (r & 3) + 8 * (r >> 2) + 4 * lh;
          float v = fmaf(sca[r] + scb[r], scale2, fmaf(slope2, (float)crow, ab));
          if (diag && crow > l31) v = -1e30f;
          s[r] = v;
        }

        float t8[8], t4[4];
#pragma unroll
        for (int i = 0; i < 8; i++) t8[i] = fmaxf(s[i], s[i + 8]);
#pragma unroll
        for (int i = 0; i < 4; i++) t4[i] = fmaxf(t8[i], t8[i + 4]);
        float mx = fmaxf(fmaxf(t4[0], t4[1]), fmaxf(t4[2], t4[3]));
        mx = fmaxf(mx, __shfl_xor(mx, 32));
        const float m2new = fmaxf(m2, mx);
        const float corr = exp2f(m2 - m2new);

        float pr[16];
#pragma unroll
        for (int r = 0; r < 16; r++) pr[r] = exp2f(s[r] - m2new);

        float a8[8], a4[4];
#pragma unroll
        for (int i = 0; i < 8; i++) a8[i] = pr[i] + pr[i + 8];
#pragma unroll
        for (int i = 0; i < 4; i++) a4[i] = a8[i] + a8[i + 4];
        float rs = (a4[0] + a4[1]) + (a4[2] + a4[3]);
        rs += __shfl_xor(rs, 32);
        l_sum = l_sum * corr + rs;
        m2 = m2new;

#pragma unroll
        for (int dt = 0; dt < 4; dt++) oacc[dt] *= corr;

        // pack P to bf16 pairs, redistribute to B-fragment layout
        unsigned int w[8];
#pragma unroll
        for (int i = 0; i < 8; i++) w[i] = packbf2(pr[2 * i], pr[2 * i + 1]);
        const unsigned int ta = __shfl_xor(lh ? w[0] : w[2], 32);
        const unsigned int tb = __shfl_xor(lh ? w[1] : w[3], 32);
        const unsigned int tc = __shfl_xor(lh ? w[4] : w[6], 32);
        const unsigned int td = __shfl_xor(lh ? w[5] : w[7], 32);
        union U4 { unsigned int u[4]; bf16x8 v; } f0, f1;
        f0.u[0] = lh ? ta : w[0];
        f0.u[1] = lh ? tb : w[1];
        f0.u[2] = lh ? w[2] : ta;
        f0.u[3] = lh ? w[3] : tb;
        f1.u[0] = lh ? tc : w[4];
        f1.u[1] = lh ? td : w[5];
        f1.u[2] = lh ? w[6] : tc;
        f1.u[3] = lh ? w[7] : td;

        __builtin_amdgcn_s_setprio(1);
#pragma unroll
        for (int dt = 0; dt < 4; dt++) {
          oacc[dt] =
              __builtin_amdgcn_mfma_f32_32x32x16_bf16(vf[dt][0], f0.v, oacc[dt], 0, 0, 0);
          oacc[dt] =
              __builtin_amdgcn_mfma_f32_32x32x16_bf16(vf[dt][1], f1.v, oacc[dt], 0, 0, 0);
        }
        __builtin_amdgcn_s_setprio(0);
      }

      __syncthreads();
      cur ^= 1;
    }

    // epilogue: O^T -> LDS transpose (overlays staging bufs; loop's final barrier
    // guarantees all waves are done reading them) -> coalesced store
    const float inv = 1.0f / l_sum;
#pragma unroll
    for (int dt = 0; dt < 4; dt++)
#pragma unroll
      for (int rg = 0; rg < 4; rg++) {
        ushort4v o;
#pragma unroll
        for (int jj = 0; jj < 4; jj++) o[jj] = f2bf(oacc[dt][rg * 4 + jj] * inv);
        *(ushort4v*)&ot[wid][l31][dt * 32 + rg * 8 + lh * 4] = o;
      }
    __syncthreads();
    const int rrow = lane >> 4, chunk = lane & 15;
#pragma unroll
    for (int ps = 0; ps < 8; ps++) {
      const int row = ps * 4 + rrow;
      ushort8 v = *(const ushort8*)&ot[wid][row][chunk * 8];
      *(ushort8*)&ao[((size_t)(b * T_SEQ + q0 + row)) * 2048 + h * HD + chunk * 8] = v;
    }
  }
}

// ---------------------------------------------------------------- launch
extern "C" void kernel_launch(void* const* d_in, const int* in_sizes, int n_in,
                              void* d_out, int out_size, void* d_ws, size_t ws_size,
                              hipStream_t stream) {
  const float* x = (const float*)d_in[0];
  const float* Wq = (const float*)d_in[1];
  const float* Wk = (const float*)d_in[2];
  const float* Wv = (const float*)d_in[3];
  const float* Wo = (const float*)d_in[4];

  char* w = (char*)d_ws;
  unsigned short* xb = (unsigned short*)w;                       // 33.5MB, reused for attn out
  unsigned short* wqt = (unsigned short*)(w + 33554432);         // 12.6MB, reused for Wo^T
  unsigned short* qb = (unsigned short*)(w + 33554432 + 12582912);
  unsigned short* kb = (unsigned short*)(w + 33554432 + 12582912 + 33554432);
  unsigned short* vtb = (unsigned short*)(w + 33554432 + 12582912 + 33554432 + 8388608);

  castx_k<<<16384, 256, 0, stream>>>(x, xb);
  transw_k<<<dim3(32, 32), 256, 0, stream>>>(Wq, wqt, 2048);
  transw_k<<<dim3(8, 32), 256, 0, stream>>>(Wk, wqt + (size_t)2048 * 2048, 512);
  transw_k<<<dim3(8, 32), 256, 0, stream>>>(Wv, wqt + (size_t)2560 * 2048, 512);
  gemm_k<0><<<dim3(64, 24), 256, 0, stream>>>(xb, wqt, qb, kb, vtb, nullptr);
  rope_k<<<40960, 256, 0, stream>>>(qb, kb);
  transw_k<<<dim3(32, 32), 256, 0, stream>>>(Wo, wqt, 2048);
  attn_k<<<512, 256, 0, stream>>>(qb, kb, vtb, xb);
  gemm_k<1><<<dim3(64, 16), 256, 0, stream>>>(xb, wqt, nullptr, nullptr, nullptr,
                                              (float*)d_out);
}

// Round 4
// 486.658 us; speedup vs baseline: 2.3791x; 1.0806x over previous
//
#include <hip/hip_runtime.h>
#include <hip/hip_bf16.h>
#include <stdint.h>

// Problem constants
#define T_SEQ 2048
#define DM    2048
#define NH    16
#define NKVH  4
#define HD    128
#define NBATCH 4
#define BT    (NBATCH * T_SEQ)   // 8192 rows of x
#define ATT_SCALE 0.08838834764831845f  // 1/sqrt(128)
#define LOG2E 1.4426950408889634f

typedef __attribute__((ext_vector_type(8))) short bf16x8;
typedef __attribute__((ext_vector_type(4))) float f32x4;
typedef __attribute__((ext_vector_type(16))) float f32x16;
typedef __attribute__((ext_vector_type(8))) unsigned short ushort8;
typedef __attribute__((ext_vector_type(4))) unsigned short ushort4v;

static __device__ __forceinline__ unsigned short f2bf(float f) {
  __hip_bfloat16 h = __float2bfloat16(f);
  return __builtin_bit_cast(unsigned short, h);
}
static __device__ __forceinline__ float bf2f(unsigned short u) {
  unsigned int v = ((unsigned int)u) << 16;
  return __builtin_bit_cast(float, v);
}
static __device__ __forceinline__ unsigned int packbf2(float a, float b) {
  return (unsigned int)f2bf(a) | ((unsigned int)f2bf(b) << 16);
}

#define GLDS16(g, l)                                                        \
  __builtin_amdgcn_global_load_lds(                                         \
      (const __attribute__((address_space(1))) void*)(g),                   \
      (__attribute__((address_space(3))) void*)(l), 16, 0, 0)

// ---------------------------------------------------------------- cast x
__global__ __launch_bounds__(256) void castx_k(const float* __restrict__ x,
                                               unsigned short* __restrict__ xb) {
  int i = (blockIdx.x * 256 + threadIdx.x) * 4;
  float4 v = *(const float4*)&x[i];
  ushort4v o;
  o[0] = f2bf(v.x); o[1] = f2bf(v.y); o[2] = f2bf(v.z); o[3] = f2bf(v.w);
  *(ushort4v*)&xb[i] = o;
}

// ------------------------------------------- cast + transpose weight (K=2048 rows)
__global__ __launch_bounds__(256) void transw_k(const float* __restrict__ src,
                                                unsigned short* __restrict__ dst,
                                                int ncols) {
  __shared__ unsigned short t[64][72];
  int n0 = blockIdx.x * 64, r0 = blockIdx.y * 64;
  int tid = threadIdx.x;
  int tx = tid & 15, ty = tid >> 4;
#pragma unroll
  for (int i = 0; i < 4; i++) {
    int r = ty * 4 + i;
    float4 v = *(const float4*)&src[(size_t)(r0 + r) * ncols + n0 + tx * 4];
    t[r][tx * 4 + 0] = f2bf(v.x);
    t[r][tx * 4 + 1] = f2bf(v.y);
    t[r][tx * 4 + 2] = f2bf(v.z);
    t[r][tx * 4 + 3] = f2bf(v.w);
  }
  __syncthreads();
  int nl = tid >> 2, seg = tid & 3;
  ushort8 o0, o1;
#pragma unroll
  for (int j = 0; j < 8; j++) {
    o0[j] = t[seg * 16 + j][nl];
    o1[j] = t[seg * 16 + 8 + j][nl];
  }
  size_t base = (size_t)(n0 + nl) * 2048 + r0 + seg * 16;
  *(ushort8*)&dst[base] = o0;
  *(ushort8*)&dst[base + 8] = o1;
}

// ---------------------------------------------------------------- GEMM (m97 structure)
template <int EPI>
__global__ __launch_bounds__(256) void gemm_k(const unsigned short* __restrict__ A,
                                              const unsigned short* __restrict__ Bt,
                                              unsigned short* __restrict__ q_out,
                                              unsigned short* __restrict__ k_out,
                                              unsigned short* __restrict__ v_out,
                                              float* __restrict__ f_out) {
  __shared__ unsigned short As[128 * 32];
  __shared__ unsigned short Bs[128 * 32];
  const int tid = threadIdx.x;
  const int lane = tid & 63;
  const int wid = tid >> 6;
  const int wr = wid >> 1, wc = wid & 1;
  const int row0 = blockIdx.x * 128, n00 = blockIdx.y * 128;
  const int lr = lane & 15, lk = (lane >> 4) * 8;
  const int c0 = tid, c1 = tid + 256;

  f32x4 acc[4][4] = {};

  for (int k0 = 0; k0 < 2048; k0 += 32) {
    __syncthreads();
    GLDS16(A + (size_t)(row0 + (c0 >> 2)) * 2048 + k0 + (c0 & 3) * 8, &As[c0 * 8]);
    GLDS16(A + (size_t)(row0 + (c1 >> 2)) * 2048 + k0 + (c1 & 3) * 8, &As[c1 * 8]);
    GLDS16(Bt + (size_t)(n00 + (c0 >> 2)) * 2048 + k0 + (c0 & 3) * 8, &Bs[c0 * 8]);
    GLDS16(Bt + (size_t)(n00 + (c1 >> 2)) * 2048 + k0 + (c1 & 3) * 8, &Bs[c1 * 8]);
    __syncthreads();
    bf16x8 af[4], bfr[4];
#pragma unroll
    for (int mi = 0; mi < 4; mi++)
      af[mi] = *(const bf16x8*)&As[(wr * 64 + mi * 16 + lr) * 32 + lk];
#pragma unroll
    for (int ni = 0; ni < 4; ni++)
      bfr[ni] = *(const bf16x8*)&Bs[(wc * 64 + ni * 16 + lr) * 32 + lk];
#pragma unroll
    for (int mi = 0; mi < 4; mi++)
#pragma unroll
      for (int ni = 0; ni < 4; ni++)
        acc[mi][ni] =
            __builtin_amdgcn_mfma_f32_16x16x32_bf16(af[mi], bfr[ni], acc[mi][ni], 0, 0, 0);
  }

  const int rbase = row0 + wr * 64;
  const int cbase = n00 + wc * 64;
#pragma unroll
  for (int mi = 0; mi < 4; mi++)
#pragma unroll
    for (int ni = 0; ni < 4; ni++)
#pragma unroll
      for (int r = 0; r < 4; r++) {
        int row = rbase + mi * 16 + (lane >> 4) * 4 + r;
        int col = cbase + ni * 16 + lr;
        float v = acc[mi][ni][r];
        if (EPI == 0) {
          if (col < 2048) {
            q_out[(size_t)row * 2048 + col] = f2bf(v);
          } else if (col < 2560) {
            k_out[(size_t)row * 512 + (col - 2048)] = f2bf(v);
          } else {
            int nv = col - 2560;
            int kvh = nv >> 7, d = nv & 127;
            int b = row >> 11, tt = row & 2047;
            v_out[((size_t)(b * NKVH + kvh) * HD + d) * T_SEQ + tt] = f2bf(v);
          }
        } else {
          f_out[(size_t)row * 2048 + col] = v;
        }
      }
}

// ---------------------------------------------------------------- RoPE (in-place, Q and K)
__global__ __launch_bounds__(256) void rope_k(unsigned short* __restrict__ qb,
                                              unsigned short* __restrict__ kb) {
  int idx = blockIdx.x * 256 + threadIdx.x;
  int i = idx & 63;
  int wi = idx >> 6;
  int hh = wi % (NH + NKVH);
  int bt = wi / (NH + NKVH);
  int t = bt & (T_SEQ - 1);
  unsigned short* p = (hh < NH) ? (qb + (size_t)bt * 2048 + hh * HD)
                                : (kb + (size_t)bt * 512 + (hh - NH) * HD);
  float theta = exp2f(-(float)i * (13.287712379549449f / 64.0f));
  float ang = (float)t * theta;
  float s, c;
  sincosf(ang, &s, &c);
  float x1 = bf2f(p[i]), x2 = bf2f(p[i + 64]);
  p[i] = f2bf(x1 * c - x2 * s);
  p[i + 64] = f2bf(x1 * s + x2 * c);
}

// ---------------------------------------------------------------- flash attention
// Unpaired triangular grid, heavy blocks first, XCD-grouped by (b,kvh).
// K-tiles streamed in REVERSE (diagonal -> 0) so the ALiBi-dominated max is in
// the first tile: defer-rescale (THR=8) then skips the O-rescale nearly always.
// K/V staged per-block in LDS (global_load_lds, XOR swizzle both sides).
// Swapped-operand 32x32 MFMA, in-register softmax, 1 shuffle per reduce.
// grid: 1024 blocks x 4 waves; each wave owns 32 q-rows.
__global__ __launch_bounds__(256) void attn_k(const unsigned short* __restrict__ qb,
                                              const unsigned short* __restrict__ kb,
                                              const unsigned short* __restrict__ vt,
                                              unsigned short* __restrict__ ao) {
  // LDS: K dbuf [2][32][128] @ 0..8191, V^T dbuf [2][128][32] @ 8192..16383 (shorts)
  // epilogue tile ot[4][32][136] overlays (barrier-separated)
  __shared__ __align__(16) unsigned short smem[17408];

  const int bid = blockIdx.x;
  const int level = bid >> 6;        // 0..15, heavy first
  const int j = 15 - level;          // q-tile (128 rows)
  const int rr = bid & 63;
  const int s8 = rr & 7;             // XCD slot
  const int w8 = rr >> 3;            // 0..7
  const int g = s8 + 8 * (w8 & 1);   // (b,kvh) group 0..15 — pinned to XCD s8
  const int hh = w8 >> 1;            // head within kv-group
  const int b = g >> 2, kvh = g & 3;
  const int h = kvh * 4 + hh;

  const int tid = threadIdx.x;
  const int wid = tid >> 6, lane = tid & 63;
  const int l31 = lane & 31, lh = lane >> 5;
  const float slope2 = exp2f(-0.5f * (float)(h + 1)) * LOG2E;
  const float scale2 = ATT_SCALE * LOG2E;

  const int q0 = j * 128 + wid * 32;
  const int dt_w = j * 4 + wid;      // this wave's diagonal tile
  const int T_blk = j * 4 + 4;       // tiles the block stages

  // staging address constants
  const int krow = tid >> 4;
  const int kchunk = tid & 15;
  const int cgk = kchunk ^ (krow & 7);
  const int vrow = tid >> 2;
  const int vchunk = tid & 3;
  const int cgv = vchunk ^ (vrow & 3);
  const int kxor = l31 & 7;
  const int vxor = l31 & 3;

  const unsigned short* khead = kb + (size_t)(b * T_SEQ) * 512 + kvh * 128;
  const unsigned short* vhead = vt + (size_t)(b * NKVH + kvh) * HD * T_SEQ;

  auto stage = [&](int buf, int k0) {
#pragma unroll
    for (int c = 0; c < 2; c++)
      GLDS16(khead + (size_t)(k0 + c * 16 + krow) * 512 + cgk * 8,
             &smem[buf * 4096 + c * 2048 + tid * 8]);
#pragma unroll
    for (int c = 0; c < 2; c++)
      GLDS16(vhead + (size_t)(c * 64 + vrow) * T_SEQ + k0 + cgv * 8,
             &smem[8192 + buf * 4096 + c * 2048 + tid * 8]);
  };

  unsigned short (*ot)[32][136] = (unsigned short(*)[32][136])smem;

  // Q fragments (B-operand): col(q)=l31, k(d)=lh*8+jj
  const unsigned short* qrow =
      qb + ((size_t)(b * T_SEQ + q0 + l31)) * 2048 + h * HD + lh * 8;
  bf16x8 qf[8];
#pragma unroll
  for (int ds = 0; ds < 8; ds++) qf[ds] = *(const bf16x8*)&qrow[ds * 16];

  f32x16 oacc[4] = {};
  float m2 = -1e30f, l_sum = 0.f;
  // per-lane ALiBi row constant: -slope2*(q0+l31)
  const float arow = -slope2 * (float)(q0 + l31);

  stage(0, 32 * (T_blk - 1));
  __syncthreads();
  int cur = 0;

#pragma unroll 1
  for (int it = 0; it < T_blk; ++it) {
    const int tt = T_blk - 1 - it;   // reverse: diagonal first
    if (it + 1 < T_blk) stage(cur ^ 1, 32 * (tt - 1));

    if (tt <= dt_w) {
      const int k0 = tt * 32;
      const unsigned short* Kb = &smem[cur * 4096];
      const unsigned short* Vb = &smem[8192 + cur * 4096];

      // K fragments (A-operand): row(key)=l31, chunk=2ds+lh, swizzled
      bf16x8 kf[8];
#pragma unroll
      for (int ds = 0; ds < 8; ds++)
        kf[ds] = *(const bf16x8*)&Kb[l31 * 128 + ((2 * ds + lh) ^ kxor) * 8];

      __builtin_amdgcn_s_setprio(1);
      f32x16 sca = 0.f, scb = 0.f;
#pragma unroll
      for (int ds = 0; ds < 4; ds++)
        sca = __builtin_amdgcn_mfma_f32_32x32x16_bf16(kf[ds], qf[ds], sca, 0, 0, 0);
#pragma unroll
      for (int ds = 4; ds < 8; ds++)
        scb = __builtin_amdgcn_mfma_f32_32x32x16_bf16(kf[ds], qf[ds], scb, 0, 0, 0);
      __builtin_amdgcn_s_setprio(0);

      // V fragments issued here: LDS latency hides under softmax
      bf16x8 vf[4][2];
#pragma unroll
      for (int dt = 0; dt < 4; dt++)
#pragma unroll
        for (int ks = 0; ks < 2; ks++)
          vf[dt][ks] =
              *(const bf16x8*)&Vb[(dt * 32 + l31) * 32 + ((2 * ks + lh) ^ vxor) * 8];

      // scores (base-2). key = k0 + crow, q = q0 + l31; full ALiBi slope*(key-q)
      float s[16];
      const float ab = fmaf(slope2, (float)k0, arow);
      const bool diag = (tt == dt_w);
#pragma unroll
      for (int r = 0; r < 16; r++) {
        const int crow = (r & 3) + 8 * (r >> 2) + 4 * lh;
        float v = fmaf(sca[r] + scb[r], scale2, fmaf(slope2, (float)crow, ab));
        if (diag && crow > l31) v = -1e30f;
        s[r] = v;
      }

      // row max (16 regs + cross-half)
      float t8[8], t4[4];
#pragma unroll
      for (int i = 0; i < 8; i++) t8[i] = fmaxf(s[i], s[i + 8]);
#pragma unroll
      for (int i = 0; i < 4; i++) t4[i] = fmaxf(t8[i], t8[i + 4]);
      float mx = fmaxf(fmaxf(t4[0], t4[1]), fmaxf(t4[2], t4[3]));
      mx = fmaxf(mx, __shfl_xor(mx, 32));

      // defer-rescale: with reverse-K the max decays — this fires ~once
      if (__any(mx > m2 + 8.f)) {
        const float mnew = fmaxf(m2, mx);
        const float corr = exp2f(m2 - mnew);
        l_sum *= corr;
#pragma unroll
        for (int dt = 0; dt < 4; dt++) oacc[dt] *= corr;
        m2 = mnew;
      }

      float pr[16];
#pragma unroll
      for (int r = 0; r < 16; r++) pr[r] = exp2f(s[r] - m2);

      float a8[8], a4[4];
#pragma unroll
      for (int i = 0; i < 8; i++) a8[i] = pr[i] + pr[i + 8];
#pragma unroll
      for (int i = 0; i < 4; i++) a4[i] = a8[i] + a8[i + 4];
      float rs = (a4[0] + a4[1]) + (a4[2] + a4[3]);
      rs += __shfl_xor(rs, 32);
      l_sum += rs;

      // pack P to bf16 pairs, redistribute to B-fragment layout
      unsigned int w[8];
#pragma unroll
      for (int i = 0; i < 8; i++) w[i] = packbf2(pr[2 * i], pr[2 * i + 1]);
      const unsigned int ta = __shfl_xor(lh ? w[0] : w[2], 32);
      const unsigned int tb = __shfl_xor(lh ? w[1] : w[3], 32);
      const unsigned int tc = __shfl_xor(lh ? w[4] : w[6], 32);
      const unsigned int td = __shfl_xor(lh ? w[5] : w[7], 32);
      union U4 { unsigned int u[4]; bf16x8 v; } f0, f1;
      f0.u[0] = lh ? ta : w[0];
      f0.u[1] = lh ? tb : w[1];
      f0.u[2] = lh ? w[2] : ta;
      f0.u[3] = lh ? w[3] : tb;
      f1.u[0] = lh ? tc : w[4];
      f1.u[1] = lh ? td : w[5];
      f1.u[2] = lh ? w[6] : tc;
      f1.u[3] = lh ? w[7] : td;

      __builtin_amdgcn_s_setprio(1);
#pragma unroll
      for (int dt = 0; dt < 4; dt++) {
        oacc[dt] =
            __builtin_amdgcn_mfma_f32_32x32x16_bf16(vf[dt][0], f0.v, oacc[dt], 0, 0, 0);
        oacc[dt] =
            __builtin_amdgcn_mfma_f32_32x32x16_bf16(vf[dt][1], f1.v, oacc[dt], 0, 0, 0);
      }
      __builtin_amdgcn_s_setprio(0);
    }

    __syncthreads();
    cur ^= 1;
  }

  // epilogue: O^T -> LDS transpose (overlays staging; final barrier above) -> store
  const float inv = 1.0f / l_sum;
#pragma unroll
  for (int dt = 0; dt < 4; dt++)
#pragma unroll
    for (int rg = 0; rg < 4; rg++) {
      ushort4v o;
#pragma unroll
      for (int jj = 0; jj < 4; jj++) o[jj] = f2bf(oacc[dt][rg * 4 + jj] * inv);
      *(ushort4v*)&ot[wid][l31][dt * 32 + rg * 8 + lh * 4] = o;
    }
  __syncthreads();
  const int rrow = lane >> 4, chunk = lane & 15;
#pragma unroll
  for (int ps = 0; ps < 8; ps++) {
    const int row = ps * 4 + rrow;
    ushort8 v = *(const ushort8*)&ot[wid][row][chunk * 8];
    *(ushort8*)&ao[((size_t)(b * T_SEQ + q0 + row)) * 2048 + h * HD + chunk * 8] = v;
  }
}

// ---------------------------------------------------------------- launch
extern "C" void kernel_launch(void* const* d_in, const int* in_sizes, int n_in,
                              void* d_out, int out_size, void* d_ws, size_t ws_size,
                              hipStream_t stream) {
  const float* x = (const float*)d_in[0];
  const float* Wq = (const float*)d_in[1];
  const float* Wk = (const float*)d_in[2];
  const float* Wv = (const float*)d_in[3];
  const float* Wo = (const float*)d_in[4];

  char* w = (char*)d_ws;
  unsigned short* xb = (unsigned short*)w;                       // 33.5MB, reused for attn out
  unsigned short* wqt = (unsigned short*)(w + 33554432);         // 12.6MB, reused for Wo^T
  unsigned short* qb = (unsigned short*)(w + 33554432 + 12582912);
  unsigned short* kb = (unsigned short*)(w + 33554432 + 12582912 + 33554432);
  unsigned short* vtb = (unsigned short*)(w + 33554432 + 12582912 + 33554432 + 8388608);

  castx_k<<<16384, 256, 0, stream>>>(x, xb);
  transw_k<<<dim3(32, 32), 256, 0, stream>>>(Wq, wqt, 2048);
  transw_k<<<dim3(8, 32), 256, 0, stream>>>(Wk, wqt + (size_t)2048 * 2048, 512);
  transw_k<<<dim3(8, 32), 256, 0, stream>>>(Wv, wqt + (size_t)2560 * 2048, 512);
  gemm_k<0><<<dim3(64, 24), 256, 0, stream>>>(xb, wqt, qb, kb, vtb, nullptr);
  rope_k<<<40960, 256, 0, stream>>>(qb, kb);
  transw_k<<<dim3(32, 32), 256, 0, stream>>>(Wo, wqt, 2048);
  attn_k<<<1024, 256, 0, stream>>>(qb, kb, vtb, xb);
  gemm_k<1><<<dim3(64, 16), 256, 0, stream>>>(xb, wqt, nullptr, nullptr, nullptr,
                                              (float*)d_out);
}

// Round 5
// 471.087 us; speedup vs baseline: 2.4577x; 1.0331x over previous
//
#include <hip/hip_runtime.h>
#include <hip/hip_bf16.h>
#include <stdint.h>

// Problem constants
#define T_SEQ 2048
#define DM    2048
#define NH    16
#define NKVH  4
#define HD    128
#define NBATCH 4
#define BT    (NBATCH * T_SEQ)   // 8192 rows of x
#define ATT_SCALE 0.08838834764831845f  // 1/sqrt(128)
#define LOG2E 1.4426950408889634f

typedef __attribute__((ext_vector_type(8))) short bf16x8;
typedef __attribute__((ext_vector_type(4))) float f32x4;
typedef __attribute__((ext_vector_type(16))) float f32x16;
typedef __attribute__((ext_vector_type(8))) unsigned short ushort8;
typedef __attribute__((ext_vector_type(4))) unsigned short ushort4v;

static __device__ __forceinline__ unsigned short f2bf(float f) {
  __hip_bfloat16 h = __float2bfloat16(f);
  return __builtin_bit_cast(unsigned short, h);
}
static __device__ __forceinline__ float bf2f(unsigned short u) {
  unsigned int v = ((unsigned int)u) << 16;
  return __builtin_bit_cast(float, v);
}
static __device__ __forceinline__ unsigned int packbf2(float a, float b) {
  return (unsigned int)f2bf(a) | ((unsigned int)f2bf(b) << 16);
}

#define GLDS16(g, l)                                                        \
  __builtin_amdgcn_global_load_lds(                                         \
      (const __attribute__((address_space(1))) void*)(g),                   \
      (__attribute__((address_space(3))) void*)(l), 16, 0, 0)

// ---------------------------------------------------------------- cast x
__global__ __launch_bounds__(256) void castx_k(const float* __restrict__ x,
                                               unsigned short* __restrict__ xb) {
  int i = (blockIdx.x * 256 + threadIdx.x) * 4;
  float4 v = *(const float4*)&x[i];
  ushort4v o;
  o[0] = f2bf(v.x); o[1] = f2bf(v.y); o[2] = f2bf(v.z); o[3] = f2bf(v.w);
  *(ushort4v*)&xb[i] = o;
}

// ------------------------------------------- cast + transpose weight (K=2048 rows)
__global__ __launch_bounds__(256) void transw_k(const float* __restrict__ src,
                                                unsigned short* __restrict__ dst,
                                                int ncols) {
  __shared__ unsigned short t[64][72];
  int n0 = blockIdx.x * 64, r0 = blockIdx.y * 64;
  int tid = threadIdx.x;
  int tx = tid & 15, ty = tid >> 4;
#pragma unroll
  for (int i = 0; i < 4; i++) {
    int r = ty * 4 + i;
    float4 v = *(const float4*)&src[(size_t)(r0 + r) * ncols + n0 + tx * 4];
    t[r][tx * 4 + 0] = f2bf(v.x);
    t[r][tx * 4 + 1] = f2bf(v.y);
    t[r][tx * 4 + 2] = f2bf(v.z);
    t[r][tx * 4 + 3] = f2bf(v.w);
  }
  __syncthreads();
  int nl = tid >> 2, seg = tid & 3;
  ushort8 o0, o1;
#pragma unroll
  for (int j = 0; j < 8; j++) {
    o0[j] = t[seg * 16 + j][nl];
    o1[j] = t[seg * 16 + 8 + j][nl];
  }
  size_t base = (size_t)(n0 + nl) * 2048 + r0 + seg * 16;
  *(ushort8*)&dst[base] = o0;
  *(ushort8*)&dst[base + 8] = o1;
}

// ---------------------------------------------------------------- GEMM (m97 structure)
template <int EPI>
__global__ __launch_bounds__(256) void gemm_k(const unsigned short* __restrict__ A,
                                              const unsigned short* __restrict__ Bt,
                                              unsigned short* __restrict__ q_out,
                                              unsigned short* __restrict__ k_out,
                                              unsigned short* __restrict__ v_out,
                                              float* __restrict__ f_out) {
  __shared__ unsigned short As[128 * 32];
  __shared__ unsigned short Bs[128 * 32];
  const int tid = threadIdx.x;
  const int lane = tid & 63;
  const int wid = tid >> 6;
  const int wr = wid >> 1, wc = wid & 1;
  const int row0 = blockIdx.x * 128, n00 = blockIdx.y * 128;
  const int lr = lane & 15, lk = (lane >> 4) * 8;
  const int c0 = tid, c1 = tid + 256;

  f32x4 acc[4][4] = {};

  for (int k0 = 0; k0 < 2048; k0 += 32) {
    __syncthreads();
    GLDS16(A + (size_t)(row0 + (c0 >> 2)) * 2048 + k0 + (c0 & 3) * 8, &As[c0 * 8]);
    GLDS16(A + (size_t)(row0 + (c1 >> 2)) * 2048 + k0 + (c1 & 3) * 8, &As[c1 * 8]);
    GLDS16(Bt + (size_t)(n00 + (c0 >> 2)) * 2048 + k0 + (c0 & 3) * 8, &Bs[c0 * 8]);
    GLDS16(Bt + (size_t)(n00 + (c1 >> 2)) * 2048 + k0 + (c1 & 3) * 8, &Bs[c1 * 8]);
    __syncthreads();
    bf16x8 af[4], bfr[4];
#pragma unroll
    for (int mi = 0; mi < 4; mi++)
      af[mi] = *(const bf16x8*)&As[(wr * 64 + mi * 16 + lr) * 32 + lk];
#pragma unroll
    for (int ni = 0; ni < 4; ni++)
      bfr[ni] = *(const bf16x8*)&Bs[(wc * 64 + ni * 16 + lr) * 32 + lk];
#pragma unroll
    for (int mi = 0; mi < 4; mi++)
#pragma unroll
      for (int ni = 0; ni < 4; ni++)
        acc[mi][ni] =
            __builtin_amdgcn_mfma_f32_16x16x32_bf16(af[mi], bfr[ni], acc[mi][ni], 0, 0, 0);
  }

  const int rbase = row0 + wr * 64;
  const int cbase = n00 + wc * 64;
#pragma unroll
  for (int mi = 0; mi < 4; mi++)
#pragma unroll
    for (int ni = 0; ni < 4; ni++)
#pragma unroll
      for (int r = 0; r < 4; r++) {
        int row = rbase + mi * 16 + (lane >> 4) * 4 + r;
        int col = cbase + ni * 16 + lr;
        float v = acc[mi][ni][r];
        if (EPI == 0) {
          if (col < 2048) {
            q_out[(size_t)row * 2048 + col] = f2bf(v);
          } else if (col < 2560) {
            k_out[(size_t)row * 512 + (col - 2048)] = f2bf(v);
          } else {
            int nv = col - 2560;
            int kvh = nv >> 7, d = nv & 127;
            int b = row >> 11, tt = row & 2047;
            v_out[((size_t)(b * NKVH + kvh) * HD + d) * T_SEQ + tt] = f2bf(v);
          }
        } else {
          f_out[(size_t)row * 2048 + col] = v;
        }
      }
}

// ---------------------------------------------------------------- RoPE (in-place, Q and K)
__global__ __launch_bounds__(256) void rope_k(unsigned short* __restrict__ qb,
                                              unsigned short* __restrict__ kb) {
  int idx = blockIdx.x * 256 + threadIdx.x;
  int i = idx & 63;
  int wi = idx >> 6;
  int hh = wi % (NH + NKVH);
  int bt = wi / (NH + NKVH);
  int t = bt & (T_SEQ - 1);
  unsigned short* p = (hh < NH) ? (qb + (size_t)bt * 2048 + hh * HD)
                                : (kb + (size_t)bt * 512 + (hh - NH) * HD);
  float theta = exp2f(-(float)i * (13.287712379549449f / 64.0f));
  float ang = (float)t * theta;
  float s, c;
  sincosf(ang, &s, &c);
  float x1 = bf2f(p[i]), x2 = bf2f(p[i + 64]);
  p[i] = f2bf(x1 * c - x2 * s);
  p[i + 64] = f2bf(x1 * s + x2 * c);
}

// ---------------------------------------------------------------- flash attention
// Paired causal grid: block does q-tiles j=p and 15-p -> uniform 34 staged
// 64-key tiles per block (512 blocks, 2/CU, zero tail). K-tiles streamed in
// REVERSE (diagonal -> 0); defer-rescale (THR=8) then almost never fires.
// K/V staged via global_load_lds with conflict-free XOR swizzle on BOTH
// operands (V now chunk^(d&7) on 128B rows — was the 17M-conflict bug).
// Swapped-operand 32x32 MFMA, in-register softmax, 1 shuffle per reduce.
__global__ __launch_bounds__(256) void attn_k(const unsigned short* __restrict__ qb,
                                              const unsigned short* __restrict__ kb,
                                              const unsigned short* __restrict__ vt,
                                              unsigned short* __restrict__ ao) {
  // shorts: K dbuf [2][64][128] @ 0..16383, V^T dbuf [2][128][64] @ 16384..32767
  // epilogue ot[4][32][136] (17408 shorts) overlays (barrier-separated)
  __shared__ __align__(16) unsigned short smem[32768];

  const int bid = blockIdx.x;
  const int s8 = bid & 7;            // XCD slot
  const int rest = bid >> 3;         // 0..63
  const int p = rest & 7;
  const int hh = (rest >> 3) & 3;
  const int g = s8 + 8 * (rest >> 5);  // (b,kvh) group, pinned to XCD s8
  const int b = g >> 2, kvh = g & 3;
  const int h = kvh * 4 + hh;

  const int tid = threadIdx.x;
  const int wid = tid >> 6, lane = tid & 63;
  const int l31 = lane & 31, lh = lane >> 5;
  const float slope2 = exp2f(-0.5f * (float)(h + 1)) * LOG2E;
  const float scale2 = ATT_SCALE * LOG2E;

  // staging constants
  const int krow = tid >> 4;                    // K: row within 16-row call
  const int cgk = (tid & 15) ^ (krow & 7);      // K source chunk (16B units)
  const int vrow7 = (tid >> 3) & 7;             // V: d&7
  const int cgv = (tid & 7) ^ vrow7;            // V source chunk
  const int xr = l31 & 7;                       // read-side xor (both K and V)

  const unsigned short* khead = kb + (size_t)(b * T_SEQ) * 512 + kvh * 128;
  const unsigned short* vhead = vt + (size_t)(b * NKVH + kvh) * HD * T_SEQ;

  auto stage = [&](int buf, int k0) {
    // K tile: 64 rows x 256B; call c covers rows c*16..c*16+15
#pragma unroll
    for (int c = 0; c < 4; c++)
      GLDS16(khead + (size_t)(k0 + c * 16 + krow) * 512 + cgk * 8,
             &smem[buf * 8192 + c * 2048 + tid * 8]);
    // V^T tile: 128 d-rows x 128B; call c covers d = c*32..c*32+31
#pragma unroll
    for (int c = 0; c < 4; c++)
      GLDS16(vhead + (size_t)(c * 32 + (tid >> 3)) * T_SEQ + k0 + cgv * 8,
             &smem[16384 + buf * 8192 + c * 2048 + tid * 8]);
  };

  unsigned short (*ot)[32][136] = (unsigned short(*)[32][136])smem;

#pragma unroll 1
  for (int half = 0; half < 2; ++half) {
    const int j = half ? (15 - p) : p;
    const int q0 = j * 128 + wid * 32;
    const int dt32 = j * 4 + wid;    // wave's diagonal 32-key block index
    const int nt = 2 * j + 2;        // 64-key tiles staged this half

    // Q fragments (B-operand): col(q)=l31, k(d)=lh*8+jj
    const unsigned short* qrow =
        qb + ((size_t)(b * T_SEQ + q0 + l31)) * 2048 + h * HD + lh * 8;
    bf16x8 qf[8];
#pragma unroll
    for (int ds = 0; ds < 8; ds++) qf[ds] = *(const bf16x8*)&qrow[ds * 16];

    f32x16 oacc[4] = {};
    float m2 = -1e30f, l_sum = 0.f;
    const float arow = -slope2 * (float)(q0 + l31);  // ALiBi row constant

    __syncthreads();                 // protect prev epilogue's LDS reads
    stage(0, 64 * (nt - 1));
    __syncthreads();
    int cur = 0;

#pragma unroll 1
    for (int it = 0; it < nt; ++it) {
      const int tt = nt - 1 - it;    // reverse: diagonal first
      if (it + 1 < nt) stage(cur ^ 1, 64 * (tt - 1));

      const unsigned short* Kb = &smem[cur * 8192];
      const unsigned short* Vb = &smem[16384 + cur * 8192];

#pragma unroll
      for (int ms = 1; ms >= 0; --ms) {
        const int k32 = tt * 2 + ms;
        if (k32 <= dt32) {
          const int k0m = k32 * 32;

          // K fragments (A-operand): row(key)=ms*32+l31, chunk o=2ds+lh
          bf16x8 kf[8];
#pragma unroll
          for (int ds = 0; ds < 8; ds++)
            kf[ds] = *(const bf16x8*)&Kb[(ms * 32 + l31) * 128 + ((2 * ds + lh) ^ xr) * 8];

          __builtin_amdgcn_s_setprio(1);
          f32x16 sc = 0.f;
#pragma unroll
          for (int ds = 0; ds < 8; ds++)
            sc = __builtin_amdgcn_mfma_f32_32x32x16_bf16(kf[ds], qf[ds], sc, 0, 0, 0);
          __builtin_amdgcn_s_setprio(0);

          // V fragments: row(d)=dt*32+l31, chunk o=ms*4+2ks+lh (LDS latency
          // hides under softmax)
          bf16x8 vf[4][2];
#pragma unroll
          for (int dt = 0; dt < 4; dt++)
#pragma unroll
            for (int ks = 0; ks < 2; ks++)
              vf[dt][ks] = *(const bf16x8*)&Vb[(dt * 32 + l31) * 64 +
                                               ((ms * 4 + 2 * ks + lh) ^ xr) * 8];

          // scores (base-2). key = k0m + crow, q = q0 + l31
          float s[16];
          const float ab = fmaf(slope2, (float)k0m, arow);
          const bool diag = (k32 == dt32);
#pragma unroll
          for (int r = 0; r < 16; r++) {
            const int crow = (r & 3) + 8 * (r >> 2) + 4 * lh;
            float v = fmaf(sc[r], scale2, fmaf(slope2, (float)crow, ab));
            if (diag && crow > l31) v = -1e30f;
            s[r] = v;
          }

          // row max (15 fmax + 1 shfl)
          float t8[8], t4[4];
#pragma unroll
          for (int i = 0; i < 8; i++) t8[i] = fmaxf(s[i], s[i + 8]);
#pragma unroll
          for (int i = 0; i < 4; i++) t4[i] = fmaxf(t8[i], t8[i + 4]);
          float mx = fmaxf(fmaxf(t4[0], t4[1]), fmaxf(t4[2], t4[3]));
          mx = fmaxf(mx, __shfl_xor(mx, 32));

          // defer-rescale: with reverse-K the max decays — fires ~once
          if (__any(mx > m2 + 8.f)) {
            const float mnew = fmaxf(m2, mx);
            const float corr = exp2f(m2 - mnew);
            l_sum *= corr;
#pragma unroll
            for (int dt = 0; dt < 4; dt++) oacc[dt] *= corr;
            m2 = mnew;
          }

          float pr[16];
#pragma unroll
          for (int r = 0; r < 16; r++) pr[r] = exp2f(s[r] - m2);

          float a8[8], a4[4];
#pragma unroll
          for (int i = 0; i < 8; i++) a8[i] = pr[i] + pr[i + 8];
#pragma unroll
          for (int i = 0; i < 4; i++) a4[i] = a8[i] + a8[i + 4];
          float rs = (a4[0] + a4[1]) + (a4[2] + a4[3]);
          rs += __shfl_xor(rs, 32);
          l_sum += rs;

          // pack P to bf16 pairs, redistribute to B-fragment layout
          unsigned int w[8];
#pragma unroll
          for (int i = 0; i < 8; i++) w[i] = packbf2(pr[2 * i], pr[2 * i + 1]);
          const unsigned int ta = __shfl_xor(lh ? w[0] : w[2], 32);
          const unsigned int tb = __shfl_xor(lh ? w[1] : w[3], 32);
          const unsigned int tc = __shfl_xor(lh ? w[4] : w[6], 32);
          const unsigned int td = __shfl_xor(lh ? w[5] : w[7], 32);
          union U4 { unsigned int u[4]; bf16x8 v; } f0, f1;
          f0.u[0] = lh ? ta : w[0];
          f0.u[1] = lh ? tb : w[1];
          f0.u[2] = lh ? w[2] : ta;
          f0.u[3] = lh ? w[3] : tb;
          f1.u[0] = lh ? tc : w[4];
          f1.u[1] = lh ? td : w[5];
          f1.u[2] = lh ? w[6] : tc;
          f1.u[3] = lh ? w[7] : td;

          __builtin_amdgcn_s_setprio(1);
#pragma unroll
          for (int dt = 0; dt < 4; dt++) {
            oacc[dt] =
                __builtin_amdgcn_mfma_f32_32x32x16_bf16(vf[dt][0], f0.v, oacc[dt], 0, 0, 0);
            oacc[dt] =
                __builtin_amdgcn_mfma_f32_32x32x16_bf16(vf[dt][1], f1.v, oacc[dt], 0, 0, 0);
          }
          __builtin_amdgcn_s_setprio(0);
        }
      }

      __syncthreads();
      cur ^= 1;
    }

    // epilogue: O^T -> LDS transpose (overlays staging; loop's final barrier
    // guarantees all waves done with staged data) -> coalesced store
    const float inv = 1.0f / l_sum;
#pragma unroll
    for (int dt = 0; dt < 4; dt++)
#pragma unroll
      for (int rg = 0; rg < 4; rg++) {
        ushort4v o;
#pragma unroll
        for (int jj = 0; jj < 4; jj++) o[jj] = f2bf(oacc[dt][rg * 4 + jj] * inv);
        *(ushort4v*)&ot[wid][l31][dt * 32 + rg * 8 + lh * 4] = o;
      }
    __syncthreads();
    const int rrow = lane >> 4, chunk = lane & 15;
#pragma unroll
    for (int ps = 0; ps < 8; ps++) {
      const int row = ps * 4 + rrow;
      ushort8 v = *(const ushort8*)&ot[wid][row][chunk * 8];
      *(ushort8*)&ao[((size_t)(b * T_SEQ + q0 + row)) * 2048 + h * HD + chunk * 8] = v;
    }
  }
}

// ---------------------------------------------------------------- launch
extern "C" void kernel_launch(void* const* d_in, const int* in_sizes, int n_in,
                              void* d_out, int out_size, void* d_ws, size_t ws_size,
                              hipStream_t stream) {
  const float* x = (const float*)d_in[0];
  const float* Wq = (const float*)d_in[1];
  const float* Wk = (const float*)d_in[2];
  const float* Wv = (const float*)d_in[3];
  const float* Wo = (const float*)d_in[4];

  char* w = (char*)d_ws;
  unsigned short* xb = (unsigned short*)w;                       // 33.5MB, reused for attn out
  unsigned short* wqt = (unsigned short*)(w + 33554432);         // 12.6MB, reused for Wo^T
  unsigned short* qb = (unsigned short*)(w + 33554432 + 12582912);
  unsigned short* kb = (unsigned short*)(w + 33554432 + 12582912 + 33554432);
  unsigned short* vtb = (unsigned short*)(w + 33554432 + 12582912 + 33554432 + 8388608);

  castx_k<<<16384, 256, 0, stream>>>(x, xb);
  transw_k<<<dim3(32, 32), 256, 0, stream>>>(Wq, wqt, 2048);
  transw_k<<<dim3(8, 32), 256, 0, stream>>>(Wk, wqt + (size_t)2048 * 2048, 512);
  transw_k<<<dim3(8, 32), 256, 0, stream>>>(Wv, wqt + (size_t)2560 * 2048, 512);
  gemm_k<0><<<dim3(64, 24), 256, 0, stream>>>(xb, wqt, qb, kb, vtb, nullptr);
  rope_k<<<40960, 256, 0, stream>>>(qb, kb);
  transw_k<<<dim3(32, 32), 256, 0, stream>>>(Wo, wqt, 2048);
  attn_k<<<512, 256, 0, stream>>>(qb, kb, vtb, xb);
  gemm_k<1><<<dim3(64, 16), 256, 0, stream>>>(xb, wqt, nullptr, nullptr, nullptr,
                                              (float*)d_out);
}